// Round 1
// baseline (22584.618 us; speedup 1.0000x reference)
//
#include <hip/hip_runtime.h>
#include <hip/hip_fp16.h>

typedef _Float16 f16;
typedef f16 f16x8 __attribute__((ext_vector_type(8)));
typedef float f32x4 __attribute__((ext_vector_type(4)));

#define B_ 64
#define T_ 512
#define I_ 256
#define O_ 1024
#define M_ 8
#define IM_ 2048
#define NREC 64
#define NACT 32
#define NB 96
#define THREADS 256

// ws layout (bytes)
#define OFF_BAR 0ull
#define OFF_W2  2048ull
#define SZ_W2   (2048ull*2304ull*2ull)
#define OFF_W1  (OFF_W2 + SZ_W2)
#define SZ_W1   (1024ull*1280ull*2ull)
#define OFF_XP  (OFF_W1 + SZ_W1)
#define SZ_XP   (2ull*64ull*2048ull*2ull)
#define OFF_H   (OFF_XP + SZ_XP)

__device__ __forceinline__ void grid_bar(unsigned* bar, unsigned target) {
    __syncthreads();
    if (threadIdx.x == 0) {
        __threadfence();
        unsigned leaf = blockIdx.x & 7u;
        unsigned old = __hip_atomic_fetch_add(&bar[leaf * 32], 1u, __ATOMIC_ACQ_REL, __HIP_MEMORY_SCOPE_AGENT);
        const unsigned per = NB / 8;
        if ((old % per) == per - 1u) {
            unsigned r = __hip_atomic_fetch_add(&bar[256], 1u, __ATOMIC_ACQ_REL, __HIP_MEMORY_SCOPE_AGENT);
            if ((r & 7u) == 7u) {
                __hip_atomic_fetch_add(&bar[257], 1u, __ATOMIC_RELEASE, __HIP_MEMORY_SCOPE_AGENT);
            }
        }
        while (__hip_atomic_load(&bar[257], __ATOMIC_ACQUIRE, __HIP_MEMORY_SCOPE_AGENT) < target) {
            __builtin_amdgcn_s_sleep(1);
        }
        __threadfence();
    }
    __syncthreads();
}

// Per-wave: two 16x16 acc tiles over cols [j0, j0+32), rows [16w, 16w+16).
// K = NC*256; chunk 0 of A comes from x (fp32, time t), chunks 1.. from stateH (fp16, row stride SR).
// W chunk staged via regs into XOR-swizzled LDS (16KB), shared by all 4 waves.
template<int NC, int SR>
__device__ __forceinline__ void gemm_tiles(
    const float* __restrict__ x, int t,
    const f16* __restrict__ stateH,
    const f16* __restrict__ Wf, int j0,
    char* lds, f32x4& acc0, f32x4& acc1)
{
    const int K = NC * 256;
    const int tid = threadIdx.x;
    const int lane = tid & 63;
    const int w = tid >> 6;
    const int rowa = w * 16 + (lane & 15);
    const int koff = (lane >> 4) * 8;
    const int c0 = lane & 15;
    const int scol = tid >> 3;                       // staging col 0..31
    const int sbase = (j0 + scol) * K + (tid & 7) * 32;

    f16x8 st[4];
    {
        const f16* p = Wf + sbase;
        #pragma unroll
        for (int q = 0; q < 4; ++q) st[q] = *(const f16x8*)(p + q * 8);
    }
    for (int n = 0; n < NC; ++n) {
        __syncthreads();   // previous chunk's LDS reads done
        #pragma unroll
        for (int q = 0; q < 4; ++q) {
            int c16 = (tid & 7) * 4 + q;
            int swz = c16 ^ (scol & 7);
            *(f16x8*)(lds + scol * 512 + swz * 16) = st[q];
        }
        __syncthreads();
        if (n + 1 < NC) {
            const f16* p = Wf + sbase + (n + 1) * 256;
            #pragma unroll
            for (int q = 0; q < 4; ++q) st[q] = *(const f16x8*)(p + q * 8);
        }
        f16x8 af[8];
        if (n == 0) {
            const float* xs = x + (rowa * T_ + t) * I_ + koff;
            #pragma unroll
            for (int ks = 0; ks < 8; ++ks) {
                f32x4 lo = *(const f32x4*)(xs + ks * 32);
                f32x4 hi = *(const f32x4*)(xs + ks * 32 + 4);
                f16x8 a;
                #pragma unroll
                for (int e = 0; e < 4; ++e) { a[e] = (f16)lo[e]; a[e + 4] = (f16)hi[e]; }
                af[ks] = a;
            }
        } else {
            const f16* as = stateH + rowa * SR + (n - 1) * 256 + koff;
            #pragma unroll
            for (int ks = 0; ks < 8; ++ks) af[ks] = *(const f16x8*)(as + ks * 32);
        }
        #pragma unroll
        for (int ks = 0; ks < 8; ++ks) {
            int c16 = ks * 4 + (lane >> 4);
            int sw = (c16 ^ (c0 & 7)) * 16;
            f16x8 b0 = *(const f16x8*)(lds + c0 * 512 + sw);
            f16x8 b1 = *(const f16x8*)(lds + (c0 + 16) * 512 + sw);
            acc0 = __builtin_amdgcn_mfma_f32_16x16x32_f16(af[ks], b0, acc0, 0, 0, 0);
            acc1 = __builtin_amdgcn_mfma_f32_16x16x32_f16(af[ks], b1, acc1, 0, 0, 0);
        }
    }
}

__global__ void init_bar_kernel(unsigned* bar) {
    bar[threadIdx.x] = 0u;   // 512 uints = 2048B, covers all counters
}

__global__ __launch_bounds__(THREADS, 1) void cwrnn_kernel(
    const float* __restrict__ x, const float* __restrict__ W_in, const float* __restrict__ b_in,
    const float* __restrict__ W_h, const float* __restrict__ W_ir, const float* __restrict__ b_ir,
    const float* __restrict__ W_hr, const float* __restrict__ periods, const float* __restrict__ shifts,
    float* __restrict__ out, char* __restrict__ ws)
{
    __shared__ char lds[16384];
    __shared__ float lse_lds[256];
    __shared__ float part_lds[256];
    __shared__ float gate_lds[64];

    unsigned* bar = (unsigned*)(ws + OFF_BAR);
    f16* W2f = (f16*)(ws + OFF_W2);
    f16* W1f = (f16*)(ws + OFF_W1);
    f16* xpH = (f16*)(ws + OFF_XP);
    f16* hH  = (f16*)(ws + OFF_H);
    float* ys   = out;
    float* hfin = out + (size_t)B_ * T_ * O_;
    float* ps   = hfin + (size_t)B_ * O_;

    const int blk = blockIdx.x, tid = threadIdx.x;

    // ---- precompute: weights -> fp16 in ws, zero fp16 state buffers ----
    for (int j = blk; j < IM_; j += NB) {
        const float* s0 = W_ir + (size_t)j * I_;
        const float* s1 = W_hr + (size_t)j * IM_;
        f16* d = W2f + (size_t)j * 2304;
        for (int k = tid; k < 2304; k += THREADS)
            d[k] = (f16)(k < 256 ? s0[k] : s1[k - 256]);
    }
    for (int j = blk; j < O_; j += NB) {
        const float* s0 = W_in + (size_t)j * I_;
        const float* s1 = W_h + (size_t)j * O_;
        f16* d = W1f + (size_t)j * 1280;
        for (int k = tid; k < 1280; k += THREADS)
            d[k] = (f16)(k < 256 ? s0[k] : s1[k - 256]);
    }
    for (int e = blk * THREADS + tid; e < 2 * B_ * IM_; e += NB * THREADS) xpH[e] = (f16)0.f;
    for (int e = blk * THREADS + tid; e < 2 * B_ * O_;  e += NB * THREADS) hH[e]  = (f16)0.f;

    grid_bar(bar, 1);

    const int lane = tid & 63;
    const int w = tid >> 6;
    const int rb = w * 16;
    const int c0 = lane & 15;
    const int rq = (lane >> 4) * 4;

    if (blk < NREC) {
        // ----- x_pred recurrence blocks: 32 cols of acts_rec each -----
        const int j0 = blk * 32;
        const float bir0 = b_ir[j0 + c0], bir1 = b_ir[j0 + 16 + c0];
        for (int t = 0; t < T_; ++t) {
            if (t == T_ - 1) break;   // final x_pred is not an output
            const int cur = t & 1, nxt = cur ^ 1;
            f32x4 acc0 = {0.f, 0.f, 0.f, 0.f}, acc1 = {0.f, 0.f, 0.f, 0.f};
            gemm_tiles<9, IM_>(x, t, xpH + (size_t)cur * B_ * IM_, W2f, j0, lds, acc0, acc1);
            f16* xd = xpH + (size_t)nxt * B_ * IM_;
            #pragma unroll
            for (int e = 0; e < 4; ++e) {
                int row = rb + rq + e;
                xd[row * IM_ + j0 + c0]      = (f16)tanhf(acc0[e] + bir0);
                xd[row * IM_ + j0 + 16 + c0] = (f16)tanhf(acc1[e] + bir1);
            }
            grid_bar(bar, t + 2);
        }
    } else {
        // ----- acts/gate/output blocks: 32 cols of acts each, one module m -----
        const int a = blk - NREC;
        const int m = a >> 2;
        const int o0 = a * 32;
        const float bin0 = b_in[o0 + c0], bin1 = b_in[o0 + 16 + c0];
        const float per = periods[m], shf = shifts[m];
        float hreg0[4] = {0.f, 0.f, 0.f, 0.f}, hreg1[4] = {0.f, 0.f, 0.f, 0.f};
        for (int t = 0; t < T_; ++t) {
            const int cur = t & 1, nxt = cur ^ 1;
            const f16* xpc = xpH + (size_t)cur * B_ * IM_ + m * 256;
            // lse over batch axis for this module's 256 features (i = tid)
            {
                int i = tid;
                float mx = -1e30f;
                #pragma unroll 8
                for (int b = 0; b < B_; ++b) mx = fmaxf(mx, (float)xpc[b * IM_ + i]);
                float s = 0.f;
                #pragma unroll 8
                for (int b = 0; b < B_; ++b) s += __expf((float)xpc[b * IM_ + i] - mx);
                lse_lds[i] = mx + __logf(s);
            }
            __syncthreads();
            // mean-surprisal partial dots: thread = (b, quarter-of-i)
            {
                int b = tid >> 2, q = tid & 3;
                const float* xrow = x + ((size_t)b * T_ + t) * I_ + q * 64;
                const f16* xprow = xpc + b * IM_ + q * 64;
                float s = 0.f;
                #pragma unroll 8
                for (int i = 0; i < 64; ++i)
                    s += ((float)xprow[i] - lse_lds[q * 64 + i]) * xrow[i];
                part_lds[tid] = s;
            }
            __syncthreads();
            if (tid < B_) {
                float s = part_lds[tid * 4] + part_lds[tid * 4 + 1] + part_lds[tid * 4 + 2] + part_lds[tid * 4 + 3];
                float mp = (s * (1.f / 256.f)) * per;
                gate_lds[tid] = 0.5f * (sinf((float)t * mp + shf) + 1.f);
                if ((a & 3) == 0) ps[((size_t)tid * T_ + t) * M_ + m] = mp;
            }
            // (gemm_tiles begins with __syncthreads -> gate_lds visible afterwards)
            f32x4 acc0 = {0.f, 0.f, 0.f, 0.f}, acc1 = {0.f, 0.f, 0.f, 0.f};
            gemm_tiles<5, O_>(x, t, hH + (size_t)cur * B_ * O_, W1f, o0, lds, acc0, acc1);
            f16* hd = hH + (size_t)nxt * B_ * O_;
            #pragma unroll
            for (int e = 0; e < 4; ++e) {
                int row = rb + rq + e;
                float g = gate_lds[row];
                float a0 = tanhf(acc0[e] + bin0);
                float a1 = tanhf(acc1[e] + bin1);
                float y0 = (1.f - g) * a0 + g * hreg0[e];
                float y1 = (1.f - g) * a1 + g * hreg1[e];
                hreg0[e] = y0; hreg1[e] = y1;
                size_t yb = ((size_t)row * T_ + t) * O_ + o0;
                ys[yb + c0] = y0;
                ys[yb + 16 + c0] = y1;
                hd[row * O_ + o0 + c0] = (f16)y0;
                hd[row * O_ + o0 + 16 + c0] = (f16)y1;
                if (t == T_ - 1) {
                    hfin[row * O_ + o0 + c0] = y0;
                    hfin[row * O_ + o0 + 16 + c0] = y1;
                }
            }
            if (t < T_ - 1) grid_bar(bar, t + 2);
        }
    }
}

extern "C" void kernel_launch(void* const* d_in, const int* in_sizes, int n_in,
                              void* d_out, int out_size, void* d_ws, size_t ws_size,
                              hipStream_t stream) {
    const float* x     = (const float*)d_in[0];
    const float* W_in  = (const float*)d_in[1];
    const float* b_in  = (const float*)d_in[2];
    const float* W_h   = (const float*)d_in[3];
    const float* W_ir  = (const float*)d_in[4];
    const float* b_ir  = (const float*)d_in[5];
    const float* W_hr  = (const float*)d_in[6];
    const float* per   = (const float*)d_in[7];
    const float* shf   = (const float*)d_in[8];

    hipLaunchKernelGGL(init_bar_kernel, dim3(1), dim3(512), 0, stream, (unsigned*)d_ws);
    hipLaunchKernelGGL(cwrnn_kernel, dim3(NB), dim3(THREADS), 0, stream,
                       x, W_in, b_in, W_h, W_ir, b_ir, W_hr, per, shf,
                       (float*)d_out, (char*)d_ws);
}

// Round 2
// 9440.485 us; speedup vs baseline: 2.3923x; 2.3923x over previous
//
#include <hip/hip_runtime.h>
#include <hip/hip_fp16.h>

typedef _Float16 f16;
typedef f16 f16x8 __attribute__((ext_vector_type(8)));
typedef float f32x4 __attribute__((ext_vector_type(4)));

#define B_ 64
#define T_ 512
#define I_ 256
#define O_ 1024
#define M_ 8
#define IM_ 2048
#define NREC 64
#define NB 96
#define THREADS 256

// ws layout (bytes)
#define OFF_BAR 0ull
#define OFF_W2  4096ull
#define SZ_W2   (2048ull*2304ull*2ull)
#define OFF_W1  (OFF_W2 + SZ_W2)
#define SZ_W1   (1024ull*1280ull*2ull)
#define OFF_XP  (OFF_W1 + SZ_W1)
#define SZ_XP   (2ull*64ull*2048ull*2ull)
#define OFF_H   (OFF_XP + SZ_XP)

#define BAR_MID  512
#define BAR_FLAG 576

#define WAITV(N) asm volatile("s_waitcnt vmcnt(" #N ")" ::: "memory")
#define LGKM0    asm volatile("s_waitcnt lgkmcnt(0)" ::: "memory")
#define SCHEDB   __builtin_amdgcn_sched_barrier(0)
#define BARRIER  __builtin_amdgcn_s_barrier()

// issue 4 x 16B cached loads (W staging), no wait
#define ISSUE4(P, S) asm volatile( \
    "global_load_dwordx4 %0, %4, off\n\t" \
    "global_load_dwordx4 %1, %4, off offset:16\n\t" \
    "global_load_dwordx4 %2, %4, off offset:32\n\t" \
    "global_load_dwordx4 %3, %4, off offset:48" \
    : "=&v"((S)[0]), "=&v"((S)[1]), "=&v"((S)[2]), "=&v"((S)[3]) \
    : "v"(P) : "memory")

// issue 8 x 16B coherent (device-scope) loads, 64B stride, no wait
#define ISSUE8C(P, A) asm volatile( \
    "global_load_dwordx4 %0, %8, off sc0 sc1\n\t" \
    "global_load_dwordx4 %1, %8, off offset:64 sc0 sc1\n\t" \
    "global_load_dwordx4 %2, %8, off offset:128 sc0 sc1\n\t" \
    "global_load_dwordx4 %3, %8, off offset:192 sc0 sc1\n\t" \
    "global_load_dwordx4 %4, %8, off offset:256 sc0 sc1\n\t" \
    "global_load_dwordx4 %5, %8, off offset:320 sc0 sc1\n\t" \
    "global_load_dwordx4 %6, %8, off offset:384 sc0 sc1\n\t" \
    "global_load_dwordx4 %7, %8, off offset:448 sc0 sc1" \
    : "=&v"((A)[0]), "=&v"((A)[1]), "=&v"((A)[2]), "=&v"((A)[3]), \
      "=&v"((A)[4]), "=&v"((A)[5]), "=&v"((A)[6]), "=&v"((A)[7]) \
    : "v"(P) : "memory")

// issue 8 x 16B coherent loads from 8 independent addresses, no wait
#define ISSUE8P(P0,P1,P2,P3,P4,P5,P6,P7, A) asm volatile( \
    "global_load_dwordx4 %0, %8, off sc0 sc1\n\t" \
    "global_load_dwordx4 %1, %9, off sc0 sc1\n\t" \
    "global_load_dwordx4 %2, %10, off sc0 sc1\n\t" \
    "global_load_dwordx4 %3, %11, off sc0 sc1\n\t" \
    "global_load_dwordx4 %4, %12, off sc0 sc1\n\t" \
    "global_load_dwordx4 %5, %13, off sc0 sc1\n\t" \
    "global_load_dwordx4 %6, %14, off sc0 sc1\n\t" \
    "global_load_dwordx4 %7, %15, off sc0 sc1" \
    : "=&v"((A)[0]), "=&v"((A)[1]), "=&v"((A)[2]), "=&v"((A)[3]), \
      "=&v"((A)[4]), "=&v"((A)[5]), "=&v"((A)[6]), "=&v"((A)[7]) \
    : "v"(P0), "v"(P1), "v"(P2), "v"(P3), "v"(P4), "v"(P5), "v"(P6), "v"(P7) \
    : "memory")

__device__ __forceinline__ void st_coh16(f16* p, f16x8 v) {
    asm volatile("global_store_dwordx4 %0, %1, off sc0 sc1" :: "v"(p), "v"(v) : "memory");
}
__device__ __forceinline__ void st_coh_h(f16* p, float vf) {
    union { f16 h; short s; } u; u.h = (f16)vf;
    asm volatile("global_store_short %0, %1, off sc0 sc1" :: "v"(p), "v"((int)u.s) : "memory");
}

// one-time full-coherence barrier (init -> loop transition)
__device__ void slow_bar(unsigned* bar, unsigned target) {
    __syncthreads();
    if (threadIdx.x == 0) {
        __threadfence();
        unsigned leaf = blockIdx.x & 7u;
        unsigned old = __hip_atomic_fetch_add(&bar[leaf * 64], 1u, __ATOMIC_ACQ_REL, __HIP_MEMORY_SCOPE_AGENT);
        const unsigned per = NB / 8;
        if ((old % per) == per - 1u) {
            unsigned r = __hip_atomic_fetch_add(&bar[BAR_MID], 1u, __ATOMIC_ACQ_REL, __HIP_MEMORY_SCOPE_AGENT);
            if ((r & 7u) == 7u)
                __hip_atomic_fetch_add(&bar[BAR_FLAG], 1u, __ATOMIC_RELEASE, __HIP_MEMORY_SCOPE_AGENT);
        }
        while (__hip_atomic_load(&bar[BAR_FLAG], __ATOMIC_ACQUIRE, __HIP_MEMORY_SCOPE_AGENT) < target)
            __builtin_amdgcn_s_sleep(2);
        __threadfence();
    }
    __syncthreads();
}

// hot-loop barrier: no cache maintenance anywhere.
// state crossing steps uses sc0/sc1 ops, so only need: my stores done (vmcnt 0
// in EVERY wave) -> block barrier -> relaxed arrival -> relaxed poll.
__device__ __forceinline__ void fast_bar(unsigned* bar, unsigned target) {
    asm volatile("s_waitcnt vmcnt(0) lgkmcnt(0)" ::: "memory");
    BARRIER;
    if (threadIdx.x == 0) {
        unsigned leaf = blockIdx.x & 7u;
        unsigned old = __hip_atomic_fetch_add(&bar[leaf * 64], 1u, __ATOMIC_RELAXED, __HIP_MEMORY_SCOPE_AGENT);
        const unsigned per = NB / 8;
        if ((old % per) == per - 1u) {
            unsigned r = __hip_atomic_fetch_add(&bar[BAR_MID], 1u, __ATOMIC_RELAXED, __HIP_MEMORY_SCOPE_AGENT);
            if ((r & 7u) == 7u)
                __hip_atomic_fetch_add(&bar[BAR_FLAG], 1u, __ATOMIC_RELAXED, __HIP_MEMORY_SCOPE_AGENT);
        }
        while (__hip_atomic_load(&bar[BAR_FLAG], __ATOMIC_RELAXED, __HIP_MEMORY_SCOPE_AGENT) < target)
            __builtin_amdgcn_s_sleep(2);
    }
    BARRIER;
}

// Software-pipelined GEMM: chunks = NS state chunks (coherent loads) then the
// x chunk (cached fp32, preloaded in prologue). Counted vmcnt, raw barriers.
template<int NS, int SR>
__device__ __forceinline__ void gemm_v2(
    const float* __restrict__ x, int t,
    const f16* __restrict__ stateH,
    const f16* __restrict__ Wf, int j0,
    char* lds, f32x4& acc0, f32x4& acc1)
{
    const int K = (NS + 1) * 256;
    const int tid = threadIdx.x;
    const int lane = tid & 63;
    const int w = tid >> 6;
    const int rowa = w * 16 + (lane & 15);
    const int koff = (lane >> 4) * 8;
    const int c0 = lane & 15;
    const int scol = tid >> 3;
    const f16* wbase = Wf + (size_t)(j0 + scol) * K + (tid & 7) * 32;
    const f16* abase = stateH + (size_t)rowa * SR + koff;

    // x-chunk A fragments: plain cached loads, fully resolved before asm issues
    f16x8 afX[8];
    {
        const float* xs = x + ((size_t)rowa * T_ + t) * I_ + koff;
        #pragma unroll
        for (int ks = 0; ks < 8; ++ks) {
            f32x4 lo = *(const f32x4*)(xs + ks * 32);
            f32x4 hi = *(const f32x4*)(xs + ks * 32 + 4);
            f16x8 a;
            #pragma unroll
            for (int e = 0; e < 4; ++e) { a[e] = (f16)lo[e]; a[e + 4] = (f16)hi[e]; }
            afX[ks] = a;
        }
    }

    f16x8 stg[2][4];
    f16x8 afg[2][8];
    ISSUE4(wbase + 256, stg[0]);   // W state-chunk 0
    ISSUE8C(abase, afg[0]);        // state chunk 0

    #pragma unroll
    for (int s = 0; s < NS; ++s) {
        const int cb = s & 1, nb = cb ^ 1;
        WAITV(8);                  // W[s] landed (af[s] = 8 newest still in flight)
        LGKM0; BARRIER;            // everyone done reading previous chunk's LDS
        #pragma unroll
        for (int q = 0; q < 4; ++q) {
            int c16 = (tid & 7) * 4 + q;
            int swz = c16 ^ (scol & 7);
            *(f16x8*)(lds + scol * 512 + swz * 16) = stg[cb][q];
        }
        LGKM0; BARRIER;            // LDS writes visible
        if (s + 1 < NS) {
            ISSUE4(wbase + 256 + (s + 1) * 256, stg[nb]);
            ISSUE8C(abase + (s + 1) * 256, afg[nb]);
            WAITV(12);             // af[s] landed, 12 newer stay in flight
        } else {
            ISSUE4(wbase, stg[nb]);   // x-chunk W
            WAITV(4);
        }
        SCHEDB;
        #pragma unroll
        for (int ks = 0; ks < 8; ++ks) {
            int c16 = ks * 4 + (lane >> 4);
            int sw = (c16 ^ (c0 & 7)) * 16;
            f16x8 b0 = *(const f16x8*)(lds + c0 * 512 + sw);
            f16x8 b1 = *(const f16x8*)(lds + (c0 + 16) * 512 + sw);
            acc0 = __builtin_amdgcn_mfma_f32_16x16x32_f16(afg[cb][ks], b0, acc0, 0, 0, 0);
            acc1 = __builtin_amdgcn_mfma_f32_16x16x32_f16(afg[cb][ks], b1, acc1, 0, 0, 0);
        }
    }
    // x chunk
    WAITV(0);
    LGKM0; BARRIER;
    {
        const int xb = NS & 1;
        #pragma unroll
        for (int q = 0; q < 4; ++q) {
            int c16 = (tid & 7) * 4 + q;
            int swz = c16 ^ (scol & 7);
            *(f16x8*)(lds + scol * 512 + swz * 16) = stg[xb][q];
        }
    }
    LGKM0; BARRIER;
    #pragma unroll
    for (int ks = 0; ks < 8; ++ks) {
        int c16 = ks * 4 + (lane >> 4);
        int sw = (c16 ^ (c0 & 7)) * 16;
        f16x8 b0 = *(const f16x8*)(lds + c0 * 512 + sw);
        f16x8 b1 = *(const f16x8*)(lds + (c0 + 16) * 512 + sw);
        acc0 = __builtin_amdgcn_mfma_f32_16x16x32_f16(afX[ks], b0, acc0, 0, 0, 0);
        acc1 = __builtin_amdgcn_mfma_f32_16x16x32_f16(afX[ks], b1, acc1, 0, 0, 0);
    }
}

__global__ void init_bar_kernel(unsigned* bar) {
    for (int i = threadIdx.x; i < 1024; i += 256) bar[i] = 0u;
}

__global__ __launch_bounds__(THREADS, 1) void cwrnn_kernel(
    const float* __restrict__ x, const float* __restrict__ W_in, const float* __restrict__ b_in,
    const float* __restrict__ W_h, const float* __restrict__ W_ir, const float* __restrict__ b_ir,
    const float* __restrict__ W_hr, const float* __restrict__ periods, const float* __restrict__ shifts,
    float* __restrict__ out, char* __restrict__ ws)
{
    __shared__ char lds[16384];
    __shared__ char xp_raw[32768];
    __shared__ float lse_lds[256];
    __shared__ float part_lds[256];
    __shared__ float gate_lds[64];

    unsigned* bar = (unsigned*)(ws + OFF_BAR);
    f16* W2f = (f16*)(ws + OFF_W2);
    f16* W1f = (f16*)(ws + OFF_W1);
    f16* xpH = (f16*)(ws + OFF_XP);
    f16* hH  = (f16*)(ws + OFF_H);
    float* ys   = out;
    float* hfin = out + (size_t)B_ * T_ * O_;
    float* ps   = hfin + (size_t)B_ * O_;

    const int blk = blockIdx.x, tid = threadIdx.x;

    // ---- weights -> fp16 (coherent stores: visible to all XCDs at coherence point) ----
    for (int j = blk; j < IM_; j += NB) {
        const float* s0 = W_ir + (size_t)j * I_;
        const float* s1 = W_hr + (size_t)j * IM_;
        f16* d = W2f + (size_t)j * 2304;
        for (int k8 = tid * 8; k8 < 2304; k8 += THREADS * 8) {
            f16x8 v;
            #pragma unroll
            for (int q = 0; q < 8; ++q) { int k = k8 + q; v[q] = (f16)(k < 256 ? s0[k] : s1[k - 256]); }
            st_coh16(d + k8, v);
        }
    }
    for (int j = blk; j < O_; j += NB) {
        const float* s0 = W_in + (size_t)j * I_;
        const float* s1 = W_h + (size_t)j * O_;
        f16* d = W1f + (size_t)j * 1280;
        for (int k8 = tid * 8; k8 < 1280; k8 += THREADS * 8) {
            f16x8 v;
            #pragma unroll
            for (int q = 0; q < 8; ++q) { int k = k8 + q; v[q] = (f16)(k < 256 ? s0[k] : s1[k - 256]); }
            st_coh16(d + k8, v);
        }
    }
    {
        f16x8 z = {0,0,0,0,0,0,0,0};
        for (int e = (blk * THREADS + tid) * 8; e < 2 * B_ * IM_; e += NB * THREADS * 8) st_coh16(xpH + e, z);
        for (int e = (blk * THREADS + tid) * 8; e < 2 * B_ * O_;  e += NB * THREADS * 8) st_coh16(hH + e, z);
    }
    slow_bar(bar, 1);

    const int lane = tid & 63;
    const int w = tid >> 6;
    const int rb = w * 16;
    const int c0 = lane & 15;
    const int rq = (lane >> 4) * 4;

    if (blk < NREC) {
        // ----- x_pred recurrence blocks: 32 cols of acts_rec each -----
        const int j0 = blk * 32;
        const float bir0 = b_ir[j0 + c0], bir1 = b_ir[j0 + 16 + c0];
        for (int t = 0; t < T_ - 1; ++t) {
            const int cur = t & 1, nxt = cur ^ 1;
            f32x4 acc0 = {0.f, 0.f, 0.f, 0.f}, acc1 = {0.f, 0.f, 0.f, 0.f};
            gemm_v2<8, IM_>(x, t, xpH + (size_t)cur * B_ * IM_, W2f, j0, lds, acc0, acc1);
            f16* xd = xpH + (size_t)nxt * B_ * IM_;
            #pragma unroll
            for (int e = 0; e < 4; ++e) {
                int row = rb + rq + e;
                st_coh_h(xd + row * IM_ + j0 + c0,      tanhf(acc0[e] + bir0));
                st_coh_h(xd + row * IM_ + j0 + 16 + c0, tanhf(acc1[e] + bir1));
            }
            fast_bar(bar, t + 2);
        }
    } else {
        // ----- acts/gate/output blocks: 32 cols of acts each, module m -----
        const int a = blk - NREC;
        const int m = a >> 2;
        const int o0 = a * 32;
        const float bin0 = b_in[o0 + c0], bin1 = b_in[o0 + 16 + c0];
        const float per = periods[m], shf = shifts[m];
        float hreg0[4] = {0.f, 0.f, 0.f, 0.f}, hreg1[4] = {0.f, 0.f, 0.f, 0.f};
        const int t5 = tid >> 5, cg = tid & 31;
        for (int t = 0; t < T_; ++t) {
            const int cur = t & 1, nxt = cur ^ 1;
            const f16* xpc = xpH + (size_t)cur * B_ * IM_ + m * 256;
            // stage module slice [64 rows x 256 cols] into XOR-swizzled LDS
            {
                f16x8 v[8];
                const f16* p0 = xpc + (size_t)(t5 +  0) * IM_ + cg * 8;
                const f16* p1 = xpc + (size_t)(t5 +  8) * IM_ + cg * 8;
                const f16* p2 = xpc + (size_t)(t5 + 16) * IM_ + cg * 8;
                const f16* p3 = xpc + (size_t)(t5 + 24) * IM_ + cg * 8;
                const f16* p4 = xpc + (size_t)(t5 + 32) * IM_ + cg * 8;
                const f16* p5 = xpc + (size_t)(t5 + 40) * IM_ + cg * 8;
                const f16* p6 = xpc + (size_t)(t5 + 48) * IM_ + cg * 8;
                const f16* p7 = xpc + (size_t)(t5 + 56) * IM_ + cg * 8;
                ISSUE8P(p0, p1, p2, p3, p4, p5, p6, p7, v);
                WAITV(0); SCHEDB;
                int gsw = (cg ^ t5) << 4;
                #pragma unroll
                for (int k = 0; k < 8; ++k)
                    *(f16x8*)(xp_raw + (size_t)(t5 + k * 8) * 512 + gsw) = v[k];
            }
            LGKM0; BARRIER;
            // lse over batch axis per feature i = tid
            {
                int i = tid;
                int g = i >> 3, r2 = (i & 7) * 2;
                float mx = -1e30f;
                #pragma unroll 8
                for (int b = 0; b < B_; ++b)
                    mx = fmaxf(mx, (float)*(const f16*)(xp_raw + b * 512 + ((g ^ (b & 7)) << 4) + r2));
                float s = 0.f;
                #pragma unroll 8
                for (int b = 0; b < B_; ++b)
                    s += __expf((float)*(const f16*)(xp_raw + b * 512 + ((g ^ (b & 7)) << 4) + r2) - mx);
                lse_lds[i] = mx + __logf(s);
            }
            LGKM0; BARRIER;
            // mean surprisal: thread = (b, quarter)
            {
                int b = tid >> 2, q = tid & 3;
                const float* xrow = x + ((size_t)b * T_ + t) * I_ + q * 64;
                float s = 0.f;
                #pragma unroll
                for (int k = 0; k < 8; ++k) {
                    f16x8 xp8 = *(const f16x8*)(xp_raw + b * 512 + (((q * 8 + k) ^ (b & 7)) << 4));
                    f32x4 xa = *(const f32x4*)(xrow + k * 8);
                    f32x4 xb = *(const f32x4*)(xrow + k * 8 + 4);
                    #pragma unroll
                    for (int jj = 0; jj < 4; ++jj)
                        s += ((float)xp8[jj] - lse_lds[q * 64 + k * 8 + jj]) * xa[jj];
                    #pragma unroll
                    for (int jj = 0; jj < 4; ++jj)
                        s += ((float)xp8[jj + 4] - lse_lds[q * 64 + k * 8 + 4 + jj]) * xb[jj];
                }
                part_lds[tid] = s;
            }
            LGKM0; BARRIER;
            if (tid < B_) {
                float s = part_lds[tid * 4] + part_lds[tid * 4 + 1] + part_lds[tid * 4 + 2] + part_lds[tid * 4 + 3];
                float mp = (s * (1.f / 256.f)) * per;
                gate_lds[tid] = 0.5f * (sinf((float)t * mp + shf) + 1.f);
                if ((a & 3) == 0) ps[((size_t)tid * T_ + t) * M_ + m] = mp;
            }
            // gate_lds made visible by gemm_v2's first internal barrier
            f32x4 acc0 = {0.f, 0.f, 0.f, 0.f}, acc1 = {0.f, 0.f, 0.f, 0.f};
            gemm_v2<4, O_>(x, t, hH + (size_t)cur * B_ * O_, W1f, o0, lds, acc0, acc1);
            f16* hd = hH + (size_t)nxt * B_ * O_;
            #pragma unroll
            for (int e = 0; e < 4; ++e) {
                int row = rb + rq + e;
                float g = gate_lds[row];
                float a0 = tanhf(acc0[e] + bin0);
                float a1 = tanhf(acc1[e] + bin1);
                float y0 = (1.f - g) * a0 + g * hreg0[e];
                float y1 = (1.f - g) * a1 + g * hreg1[e];
                hreg0[e] = y0; hreg1[e] = y1;
                size_t yb = ((size_t)row * T_ + t) * O_ + o0;
                ys[yb + c0] = y0;
                ys[yb + 16 + c0] = y1;
                st_coh_h(hd + row * O_ + o0 + c0,      y0);
                st_coh_h(hd + row * O_ + o0 + 16 + c0, y1);
                if (t == T_ - 1) {
                    hfin[row * O_ + o0 + c0] = y0;
                    hfin[row * O_ + o0 + 16 + c0] = y1;
                }
            }
            if (t < T_ - 1) fast_bar(bar, t + 2);
        }
    }
}

extern "C" void kernel_launch(void* const* d_in, const int* in_sizes, int n_in,
                              void* d_out, int out_size, void* d_ws, size_t ws_size,
                              hipStream_t stream) {
    const float* x     = (const float*)d_in[0];
    const float* W_in  = (const float*)d_in[1];
    const float* b_in  = (const float*)d_in[2];
    const float* W_h   = (const float*)d_in[3];
    const float* W_ir  = (const float*)d_in[4];
    const float* b_ir  = (const float*)d_in[5];
    const float* W_hr  = (const float*)d_in[6];
    const float* per   = (const float*)d_in[7];
    const float* shf   = (const float*)d_in[8];

    hipLaunchKernelGGL(init_bar_kernel, dim3(1), dim3(256), 0, stream, (unsigned*)d_ws);
    hipLaunchKernelGGL(cwrnn_kernel, dim3(NB), dim3(THREADS), 0, stream,
                       x, W_in, b_in, W_h, W_ir, b_ir, W_hr, per, shf,
                       (float*)d_out, (char*)d_ws);
}

// Round 4
// 9165.378 us; speedup vs baseline: 2.4641x; 1.0300x over previous
//
#include <hip/hip_runtime.h>
#include <hip/hip_fp16.h>

typedef _Float16 f16;
typedef f16 f16x8 __attribute__((ext_vector_type(8)));
typedef f16 f16x4 __attribute__((ext_vector_type(4)));
typedef float f32x4 __attribute__((ext_vector_type(4)));
typedef float f32x16 __attribute__((ext_vector_type(16)));

#define B_ 64
#define T_ 512
#define I_ 256
#define O_ 1024
#define M_ 8
#define IM_ 2048
#define NREC 64
#define NB 96
#define THREADS 256

// ws layout (bytes)
#define OFF_X16 4096ull
#define SZ_X16  ((unsigned long long)T_ * B_ * I_ * 2)   // 16 MB, [T][B][I] f16
#define OFF_XP3 (OFF_X16 + SZ_X16)                       // 3 x [B][IM] f16
#define SZ_XP3  (3ull * B_ * IM_ * 2)
#define OFF_H2  (OFF_XP3 + SZ_XP3)                       // 2 x [B][O] f16

// barrier uint indices (64B-separated lines)
#define MIDA  128
#define FLAGA 144
#define MIDB  288
#define FLAGB 304

#define WAITV(N) asm volatile("s_waitcnt vmcnt(" #N ")" ::: "memory")
#define LGKM0    asm volatile("s_waitcnt lgkmcnt(0)" ::: "memory")
#define BARRIER  __builtin_amdgcn_s_barrier()

// 8 x 16B loads at 32B stride, cached (x16 input)
#define ISSUE_AX(BUF, P) asm volatile( \
    "global_load_dwordx4 %0, %8, off\n\t" \
    "global_load_dwordx4 %1, %8, off offset:32\n\t" \
    "global_load_dwordx4 %2, %8, off offset:64\n\t" \
    "global_load_dwordx4 %3, %8, off offset:96\n\t" \
    "global_load_dwordx4 %4, %8, off offset:128\n\t" \
    "global_load_dwordx4 %5, %8, off offset:160\n\t" \
    "global_load_dwordx4 %6, %8, off offset:192\n\t" \
    "global_load_dwordx4 %7, %8, off offset:224" \
    : "=&v"(abuf[BUF][0]), "=&v"(abuf[BUF][1]), "=&v"(abuf[BUF][2]), "=&v"(abuf[BUF][3]), \
      "=&v"(abuf[BUF][4]), "=&v"(abuf[BUF][5]), "=&v"(abuf[BUF][6]), "=&v"(abuf[BUF][7]) \
    : "v"(P) : "memory")

// 8 x 16B loads at 32B stride, coherent (cross-XCD state)
#define ISSUE_AS(BUF, P) asm volatile( \
    "global_load_dwordx4 %0, %8, off sc0 sc1\n\t" \
    "global_load_dwordx4 %1, %8, off offset:32 sc0 sc1\n\t" \
    "global_load_dwordx4 %2, %8, off offset:64 sc0 sc1\n\t" \
    "global_load_dwordx4 %3, %8, off offset:96 sc0 sc1\n\t" \
    "global_load_dwordx4 %4, %8, off offset:128 sc0 sc1\n\t" \
    "global_load_dwordx4 %5, %8, off offset:160 sc0 sc1\n\t" \
    "global_load_dwordx4 %6, %8, off offset:192 sc0 sc1\n\t" \
    "global_load_dwordx4 %7, %8, off offset:224 sc0 sc1" \
    : "=&v"(abuf[BUF][0]), "=&v"(abuf[BUF][1]), "=&v"(abuf[BUF][2]), "=&v"(abuf[BUF][3]), \
      "=&v"(abuf[BUF][4]), "=&v"(abuf[BUF][5]), "=&v"(abuf[BUF][6]), "=&v"(abuf[BUF][7]) \
    : "v"(P) : "memory")

#define ISSUE_STG8(P0,P1,P2,P3,P4,P5,P6,P7) asm volatile( \
    "global_load_dwordx4 %0, %8, off sc0 sc1\n\t" \
    "global_load_dwordx4 %1, %9, off sc0 sc1\n\t" \
    "global_load_dwordx4 %2, %10, off sc0 sc1\n\t" \
    "global_load_dwordx4 %3, %11, off sc0 sc1\n\t" \
    "global_load_dwordx4 %4, %12, off sc0 sc1\n\t" \
    "global_load_dwordx4 %5, %13, off sc0 sc1\n\t" \
    "global_load_dwordx4 %6, %14, off sc0 sc1\n\t" \
    "global_load_dwordx4 %7, %15, off sc0 sc1" \
    : "=&v"(sreg[0]), "=&v"(sreg[1]), "=&v"(sreg[2]), "=&v"(sreg[3]), \
      "=&v"(sreg[4]), "=&v"(sreg[5]), "=&v"(sreg[6]), "=&v"(sreg[7]) \
    : "v"(P0), "v"(P1), "v"(P2), "v"(P3), "v"(P4), "v"(P5), "v"(P6), "v"(P7) \
    : "memory")

// prologue issue of chunk c0+J into buffer J (x-cached if c<2, else coherent state)
#define GM_PRO(J) do { \
    const int c_ = c0 + (J); \
    if (c_ < 2) { const char* p_ = xrow + c_ * 256;  ISSUE_AX(J, p_); } \
    else        { const char* p_ = sprow + c_ * 256; ISSUE_AS(J, p_); } \
} while (0)

// one chunk iteration: counted wait, optional reissue 6 ahead, 8x (ds_read_b128 + MFMA)
#define GM_IT(I, WN, DOISS) do { \
    WAITV(WN); \
    if (DOISS) { const char* p_ = sprow + (c0 + (I) + 6) * 256; ISSUE_AS((((I) + 6) % 7), p_); } \
    _Pragma("unroll") \
    for (int kb = 0; kb < 8; ++kb) { \
        f16x8 bf = *(const f16x8*)(smem + addrB[kb] + (I) * 256); \
        if (kb & 1) acc1 = __builtin_amdgcn_mfma_f32_32x32x16_f16(abuf[(I) % 7][kb], bf, acc1, 0, 0, 0); \
        else        acc0 = __builtin_amdgcn_mfma_f32_32x32x16_f16(abuf[(I) % 7][kb], bf, acc0, 0, 0, 0); \
    } \
} while (0)

__device__ __forceinline__ void st_coh_h(f16* p, float vf) {
    union { f16 h; short s; } u; u.h = (f16)vf;
    asm volatile("global_store_short %0, %1, off sc0 sc1" :: "v"(p), "v"((int)u.s) : "memory");
}

__device__ __forceinline__ float fast_tanh(float x) {
    float e = __expf(2.f * x);
    return 1.f - 2.f / (e + 1.f);
}

__device__ __forceinline__ unsigned ld_rlx(unsigned* p) {
    return __hip_atomic_load(p, __ATOMIC_RELAXED, __HIP_MEMORY_SCOPE_AGENT);
}

__device__ __forceinline__ void arriveA(unsigned* bar, int blk) {
    unsigned old = __hip_atomic_fetch_add(&bar[(blk & 7) * 16], 1u, __ATOMIC_RELAXED, __HIP_MEMORY_SCOPE_AGENT);
    if ((old & 7u) == 7u) {
        unsigned r = __hip_atomic_fetch_add(&bar[MIDA], 1u, __ATOMIC_RELAXED, __HIP_MEMORY_SCOPE_AGENT);
        if ((r & 7u) == 7u)
            __hip_atomic_fetch_add(&bar[FLAGA], 1u, __ATOMIC_RELAXED, __HIP_MEMORY_SCOPE_AGENT);
    }
}
__device__ __forceinline__ void arriveB(unsigned* bar, int a) {
    unsigned old = __hip_atomic_fetch_add(&bar[160 + (a & 7) * 16], 1u, __ATOMIC_RELAXED, __HIP_MEMORY_SCOPE_AGENT);
    if ((old & 3u) == 3u) {
        unsigned r = __hip_atomic_fetch_add(&bar[MIDB], 1u, __ATOMIC_RELAXED, __HIP_MEMORY_SCOPE_AGENT);
        if ((r & 7u) == 7u)
            __hip_atomic_fetch_add(&bar[FLAGB], 1u, __ATOMIC_RELAXED, __HIP_MEMORY_SCOPE_AGENT);
    }
}

// init: zero barriers+state, convert x [B,T,I] f32 -> x16 [T,B,I] f16
__global__ void init_kernel(const float* __restrict__ x, char* __restrict__ ws) {
    const int gid = blockIdx.x * THREADS + threadIdx.x;
    // FIX(R4): zero ALL 512 barrier words (R3 zeroed only 256 -> FLAGB/MIDB
    // kept 0xAA poison -> negative flag -> grid-wide deadlock)
    if (blockIdx.x == 0) {
        for (int i = threadIdx.x; i < 512; i += THREADS) ((unsigned*)ws)[i] = 0u;
    }
    f16* x16 = (f16*)(ws + OFF_X16);
    const int NQ = T_ * B_ * (I_ / 4);
    for (int q = gid; q < NQ; q += 256 * THREADS) {
        int t = q >> 12;              // / (B_*I_/4)
        int rem = q & 4095;
        int b = rem >> 6;
        int k4 = rem & 63;
        f32x4 v = *(const f32x4*)(x + ((size_t)b * T_ + t) * I_ + k4 * 4);
        f16x4 h;
        h[0] = (f16)v[0]; h[1] = (f16)v[1]; h[2] = (f16)v[2]; h[3] = (f16)v[3];
        *(f16x4*)(x16 + ((size_t)t * B_ + b) * I_ + k4 * 4) = h;
    }
    f16x8 z = {0, 0, 0, 0, 0, 0, 0, 0};
    f16* xp0 = (f16*)(ws + OFF_XP3);
    for (int e = gid * 8; e < B_ * IM_; e += 256 * THREADS * 8) *(f16x8*)(xp0 + e) = z;
    f16* h0 = (f16*)(ws + OFF_H2);
    for (int e = gid * 8; e < B_ * O_; e += 256 * THREADS * 8) *(f16x8*)(h0 + e) = z;
}

__global__ __launch_bounds__(THREADS, 1) void cwrnn_kernel(
    const float* __restrict__ x, const float* __restrict__ W_in, const float* __restrict__ b_in,
    const float* __restrict__ W_h, const float* __restrict__ W_ir, const float* __restrict__ b_ir,
    const float* __restrict__ W_hr, const float* __restrict__ periods, const float* __restrict__ shifts,
    float* __restrict__ out, char* __restrict__ ws)
{
    __shared__ __align__(16) char smem[157696];
    // REC: W[32][2304] swz @0 (147456) | accx @147456 (10240)
    // ACT: W[32][1280] swz @0 (81920) | xp_raw @81920 (32768) | accx @114688 (10240)
    //      lse @124928 | part @125952 | gate @126976

    unsigned* bar = (unsigned*)ws;
    const int blk = blockIdx.x, tid = threadIdx.x;
    const int lane = tid & 63, w = tid >> 6;
    const int col = lane & 31, g = lane >> 5;
    const int pair = w >> 1;
    const int arow = ((w & 1) << 5) + col;

    float* ys = out;
    float* hfin = out + (size_t)B_ * T_ * O_;
    float* ps = hfin + (size_t)B_ * O_;

    if (blk < NREC) {
        // ================= x_pred recurrence blocks: cols j0..j0+31 of acts_rec =================
        const int j0 = blk * 32;
        {   // stage W2 = [W_ir | W_hr] rows j0..j0+31 into swizzled LDS (once)
            const int j = tid >> 3;
            const float* ra = W_ir + (size_t)(j0 + j) * I_;
            const float* rb = W_hr + (size_t)(j0 + j) * IM_ - 256;
            for (int u = (tid & 7); u < 288; u += 8) {
                int k0 = u * 8;
                const float* s = (k0 < 256) ? (ra + k0) : (rb + k0);
                f32x4 lo = *(const f32x4*)s;
                f32x4 hi = *(const f32x4*)(s + 4);
                f16x8 v;
                #pragma unroll
                for (int e = 0; e < 4; ++e) { v[e] = (f16)lo[e]; v[e + 4] = (f16)hi[e]; }
                *(f16x8*)(smem + j * 4608 + ((u ^ (j & 15)) << 4)) = v;
            }
        }
        const float bir = b_ir[j0 + col];
        LGKM0; BARRIER;

        int addrB[8];
        const int c0 = pair * 9;
        #pragma unroll
        for (int kb = 0; kb < 8; ++kb)
            addrB[kb] = col * 4608 + ((((kb << 1) + g) ^ (col & 15)) << 4) + c0 * 256;

        const char* xrow0 = (const char*)(ws + OFF_X16) + (size_t)arow * 512 + g * 16;
        f16* const xpB = (f16*)(ws + OFF_XP3);

        for (int t = 0; t < T_ - 1; ++t) {
            if (tid == 0) {
                while ((int)ld_rlx(&bar[FLAGA]) < t) __builtin_amdgcn_s_sleep(1);
                while ((int)ld_rlx(&bar[FLAGB]) < t - 1) __builtin_amdgcn_s_sleep(1);
            }
            BARRIER;
            const int bi = t % 3;
            int bn = bi + 1; if (bn == 3) bn = 0;
            const f16* xpcur = xpB + (size_t)bi * B_ * IM_;
            f16* xpnxt = xpB + (size_t)bn * B_ * IM_;
            const char* sprow = (const char*)xpcur + (size_t)arow * 4096 + g * 16 - 512;
            const char* xrow = xrow0 + (size_t)t * 32768;

            f16x8 abuf[7][8];
            f32x16 acc0, acc1;
            #pragma unroll
            for (int r = 0; r < 16; ++r) { acc0[r] = 0.f; acc1[r] = 0.f; }

            GM_PRO(0); GM_PRO(1); GM_PRO(2); GM_PRO(3); GM_PRO(4); GM_PRO(5);
            GM_IT(0, 40, 1); GM_IT(1, 40, 1); GM_IT(2, 40, 1); GM_IT(3, 40, 0);
            GM_IT(4, 32, 0); GM_IT(5, 24, 0); GM_IT(6, 16, 0); GM_IT(7, 8, 0); GM_IT(8, 0, 0);

            f32x16 accS;
            #pragma unroll
            for (int r = 0; r < 16; ++r) accS[r] = acc0[r] + acc1[r];
            if (w >= 2) {
                char* axp = smem + 147456 + (w - 2) * 5120 + lane * 80;
                #pragma unroll
                for (int q = 0; q < 4; ++q) {
                    f32x4 v = { accS[q * 4 + 0], accS[q * 4 + 1], accS[q * 4 + 2], accS[q * 4 + 3] };
                    *(f32x4*)(axp + q * 16) = v;
                }
            }
            LGKM0; BARRIER;
            if (w < 2) {
                const char* axp = smem + 147456 + w * 5120 + lane * 80;
                #pragma unroll
                for (int q = 0; q < 4; ++q) {
                    f32x4 v = *(const f32x4*)(axp + q * 16);
                    accS[q * 4 + 0] += v[0]; accS[q * 4 + 1] += v[1];
                    accS[q * 4 + 2] += v[2]; accS[q * 4 + 3] += v[3];
                }
                #pragma unroll
                for (int r = 0; r < 16; ++r) {
                    int row = (r & 3) + ((r >> 2) << 3) + (g << 2) + (w << 5);
                    st_coh_h(xpnxt + (size_t)row * IM_ + j0 + col, fast_tanh(accS[r] + bir));
                }
            }
            WAITV(0);
            BARRIER;
            if (tid == 0) { arriveA(bar, blk); WAITV(0); }
        }
    } else {
        // ================= acts/gate/output blocks: cols o0..o0+31 =================
        const int a = blk - NREC;
        const int m = a >> 2;
        const int o0 = a * 32;
        {   // stage W1 = [W_in | W_h] rows o0..o0+31
            const int j = tid >> 3;
            const float* ra = W_in + (size_t)(o0 + j) * I_;
            const float* rb = W_h + (size_t)(o0 + j) * O_ - 256;
            for (int u = (tid & 7); u < 160; u += 8) {
                int k0 = u * 8;
                const float* s = (k0 < 256) ? (ra + k0) : (rb + k0);
                f32x4 lo = *(const f32x4*)s;
                f32x4 hi = *(const f32x4*)(s + 4);
                f16x8 v;
                #pragma unroll
                for (int e = 0; e < 4; ++e) { v[e] = (f16)lo[e]; v[e + 4] = (f16)hi[e]; }
                *(f16x8*)(smem + j * 2560 + ((u ^ (j & 15)) << 4)) = v;
            }
        }
        const float bin = b_in[o0 + col];
        const float per = periods[m], shf = shifts[m];
        LGKM0; BARRIER;

        int addrB[8];
        const int c0 = pair * 5;
        #pragma unroll
        for (int kb = 0; kb < 8; ++kb)
            addrB[kb] = col * 2560 + ((((kb << 1) + g) ^ (col & 15)) << 4) + c0 * 256;

        char* xp_raw = smem + 81920;
        float* lse_lds = (float*)(smem + 124928);
        float* part_lds = (float*)(smem + 125952);
        float* gate_lds = (float*)(smem + 126976);

        const char* xrow0 = (const char*)(ws + OFF_X16) + (size_t)arow * 512 + g * 16;
        const f16* xpB = (const f16*)(ws + OFF_XP3);
        f16* h2 = (f16*)(ws + OFF_H2);
        const int t5 = tid >> 5, cg = tid & 31;
        float hreg[16];
        #pragma unroll
        for (int r = 0; r < 16; ++r) hreg[r] = 0.f;

        for (int t = 0; t < T_; ++t) {
            if (tid == 0) {
                while ((int)ld_rlx(&bar[FLAGB]) < t) __builtin_amdgcn_s_sleep(1);
                while ((int)ld_rlx(&bar[FLAGA]) < t) __builtin_amdgcn_s_sleep(1);
            }
            BARRIER;
            const int bi = t % 3;
            const f16* xpcur = xpB + (size_t)bi * B_ * IM_;
            const f16* hcur = h2 + (size_t)(t & 1) * B_ * O_;
            f16* hnxt = h2 + (size_t)((t + 1) & 1) * B_ * O_;

            // issue softmax-slice staging loads first (latency hidden under GEMM)
            f16x8 sreg[8];
            {
                const char* sb = (const char*)xpcur + (size_t)m * 512 + (size_t)cg * 16 + (size_t)t5 * 4096;
                ISSUE_STG8(sb, sb + 32768, sb + 2 * 32768, sb + 3 * 32768,
                           sb + 4 * 32768, sb + 5 * 32768, sb + 6 * 32768, sb + 7 * 32768);
            }

            const char* sprow = (const char*)hcur + (size_t)arow * 2048 + g * 16 - 512;
            const char* xrow = xrow0 + (size_t)t * 32768;
            f16x8 abuf[7][8];
            f32x16 acc0, acc1;
            #pragma unroll
            for (int r = 0; r < 16; ++r) { acc0[r] = 0.f; acc1[r] = 0.f; }

            GM_PRO(0); GM_PRO(1); GM_PRO(2); GM_PRO(3); GM_PRO(4);
            GM_IT(0, 32, 0);
            {   // staging regs landed with chunk 0 — park them in swizzled xp_raw
                const int gsw = (cg ^ t5) << 4;
                #pragma unroll
                for (int k = 0; k < 8; ++k)
                    *(f16x8*)(xp_raw + (size_t)(t5 + (k << 3)) * 512 + gsw) = sreg[k];
            }
            GM_IT(1, 24, 0); GM_IT(2, 16, 0); GM_IT(3, 8, 0); GM_IT(4, 0, 0);

            f32x16 accS;
            #pragma unroll
            for (int r = 0; r < 16; ++r) accS[r] = acc0[r] + acc1[r];
            if (w >= 2) {
                char* axp = smem + 114688 + (w - 2) * 5120 + lane * 80;
                #pragma unroll
                for (int q = 0; q < 4; ++q) {
                    f32x4 v = { accS[q * 4 + 0], accS[q * 4 + 1], accS[q * 4 + 2], accS[q * 4 + 3] };
                    *(f32x4*)(axp + q * 16) = v;
                }
            }
            LGKM0; BARRIER;
            {   // lse over batch axis, feature i = tid
                int i = tid;
                int gq = i >> 3, r2 = (i & 7) * 2;
                float mx = -1e30f;
                #pragma unroll 8
                for (int b = 0; b < B_; ++b)
                    mx = fmaxf(mx, (float)*(const f16*)(xp_raw + b * 512 + ((gq ^ (b & 7)) << 4) + r2));
                float s = 0.f;
                #pragma unroll 8
                for (int b = 0; b < B_; ++b)
                    s += __expf((float)*(const f16*)(xp_raw + b * 512 + ((gq ^ (b & 7)) << 4) + r2) - mx);
                lse_lds[i] = mx + __logf(s);
            }
            LGKM0; BARRIER;
            {   // mean surprisal partial dots: thread = (b, quarter)
                int b = tid >> 2, q = tid & 3;
                const float* xr = x + ((size_t)b * T_ + t) * I_ + q * 64;
                float s = 0.f;
                #pragma unroll
                for (int k = 0; k < 8; ++k) {
                    f16x8 xp8 = *(const f16x8*)(xp_raw + (size_t)b * 512 + ((((q << 3) + k) ^ (b & 7)) << 4));
                    f32x4 xa = *(const f32x4*)(xr + k * 8);
                    f32x4 xb2 = *(const f32x4*)(xr + k * 8 + 4);
                    #pragma unroll
                    for (int jj = 0; jj < 4; ++jj)
                        s += ((float)xp8[jj] - lse_lds[(q << 6) + (k << 3) + jj]) * xa[jj];
                    #pragma unroll
                    for (int jj = 0; jj < 4; ++jj)
                        s += ((float)xp8[jj + 4] - lse_lds[(q << 6) + (k << 3) + 4 + jj]) * xb2[jj];
                }
                part_lds[tid] = s;
            }
            LGKM0; BARRIER;
            if (tid < B_) {
                float s = part_lds[tid * 4] + part_lds[tid * 4 + 1] + part_lds[tid * 4 + 2] + part_lds[tid * 4 + 3];
                float mp = (s * (1.f / 256.f)) * per;
                gate_lds[tid] = 0.5f * (sinf((float)t * mp + shf) + 1.f);
                if ((a & 3) == 0) ps[((size_t)tid * T_ + t) * M_ + m] = mp;
            }
            LGKM0; BARRIER;
            if (w < 2) {
                const char* axp = smem + 114688 + w * 5120 + lane * 80;
                #pragma unroll
                for (int q = 0; q < 4; ++q) {
                    f32x4 v = *(const f32x4*)(axp + q * 16);
                    accS[q * 4 + 0] += v[0]; accS[q * 4 + 1] += v[1];
                    accS[q * 4 + 2] += v[2]; accS[q * 4 + 3] += v[3];
                }
                #pragma unroll
                for (int r = 0; r < 16; ++r) {
                    int row = (r & 3) + ((r >> 2) << 3) + (g << 2) + (w << 5);
                    float gt = gate_lds[row];
                    float av = fast_tanh(accS[r] + bin);
                    float y = (1.f - gt) * av + gt * hreg[r];
                    hreg[r] = y;
                    ys[((size_t)row * T_ + t) * O_ + o0 + col] = y;
                    st_coh_h(hnxt + (size_t)row * O_ + o0 + col, y);
                    if (t == T_ - 1) hfin[(size_t)row * O_ + o0 + col] = y;
                }
            }
            WAITV(0);
            BARRIER;
            if (tid == 0) { arriveB(bar, a); WAITV(0); }
        }
    }
}

extern "C" void kernel_launch(void* const* d_in, const int* in_sizes, int n_in,
                              void* d_out, int out_size, void* d_ws, size_t ws_size,
                              hipStream_t stream) {
    const float* x    = (const float*)d_in[0];
    const float* W_in = (const float*)d_in[1];
    const float* b_in = (const float*)d_in[2];
    const float* W_h  = (const float*)d_in[3];
    const float* W_ir = (const float*)d_in[4];
    const float* b_ir = (const float*)d_in[5];
    const float* W_hr = (const float*)d_in[6];
    const float* per  = (const float*)d_in[7];
    const float* shf  = (const float*)d_in[8];

    hipLaunchKernelGGL(init_kernel, dim3(256), dim3(THREADS), 0, stream,
                       x, (char*)d_ws);
    hipLaunchKernelGGL(cwrnn_kernel, dim3(NB), dim3(THREADS), 0, stream,
                       x, W_in, b_in, W_h, W_ir, b_ir, W_hr, per, shf,
                       (float*)d_out, (char*)d_ws);
}

// Round 5
// 8840.324 us; speedup vs baseline: 2.5547x; 1.0368x over previous
//
#include <hip/hip_runtime.h>
#include <hip/hip_fp16.h>

typedef _Float16 f16;
typedef f16 f16x8 __attribute__((ext_vector_type(8)));
typedef f16 f16x4 __attribute__((ext_vector_type(4)));
typedef float f32x4 __attribute__((ext_vector_type(4)));
typedef float f32x16 __attribute__((ext_vector_type(16)));

#define B_ 64
#define T_ 512
#define I_ 256
#define O_ 1024
#define M_ 8
#define IM_ 2048
#define NREC 64
#define NB 96
#define THREADS 256

// ws layout (bytes)
#define OFF_X16 4096ull
#define SZ_X16  ((unsigned long long)T_ * B_ * I_ * 2)   // 16 MB, [T][B][I] f16
#define OFF_XP3 (OFF_X16 + SZ_X16)                       // 3 x [B][IM] f16
#define SZ_XP3  (3ull * B_ * IM_ * 2)
#define OFF_H2  (OFF_XP3 + SZ_XP3)                       // 2 x [B][O] f16

// barrier uint indices (64B-separated lines)
#define MIDA  128
#define FLAGA 144
#define MIDB  288
#define FLAGB 304

#define WAITV(N) asm volatile("s_waitcnt vmcnt(" #N ")" ::: "memory")
#define LGKM0    asm volatile("s_waitcnt lgkmcnt(0)" ::: "memory")
#define SCHEDB   __builtin_amdgcn_sched_barrier(0)
#define BARRIER  __builtin_amdgcn_s_barrier()

// 8 x 16B loads at 32B stride, cached (x16 input)
#define ISSUE_AX(BUF, P) asm volatile( \
    "global_load_dwordx4 %0, %8, off\n\t" \
    "global_load_dwordx4 %1, %8, off offset:32\n\t" \
    "global_load_dwordx4 %2, %8, off offset:64\n\t" \
    "global_load_dwordx4 %3, %8, off offset:96\n\t" \
    "global_load_dwordx4 %4, %8, off offset:128\n\t" \
    "global_load_dwordx4 %5, %8, off offset:160\n\t" \
    "global_load_dwordx4 %6, %8, off offset:192\n\t" \
    "global_load_dwordx4 %7, %8, off offset:224" \
    : "=&v"(abuf[BUF][0]), "=&v"(abuf[BUF][1]), "=&v"(abuf[BUF][2]), "=&v"(abuf[BUF][3]), \
      "=&v"(abuf[BUF][4]), "=&v"(abuf[BUF][5]), "=&v"(abuf[BUF][6]), "=&v"(abuf[BUF][7]) \
    : "v"(P) : "memory")

// 8 x 16B loads at 32B stride, coherent (cross-XCD state)
#define ISSUE_AS(BUF, P) asm volatile( \
    "global_load_dwordx4 %0, %8, off sc0 sc1\n\t" \
    "global_load_dwordx4 %1, %8, off offset:32 sc0 sc1\n\t" \
    "global_load_dwordx4 %2, %8, off offset:64 sc0 sc1\n\t" \
    "global_load_dwordx4 %3, %8, off offset:96 sc0 sc1\n\t" \
    "global_load_dwordx4 %4, %8, off offset:128 sc0 sc1\n\t" \
    "global_load_dwordx4 %5, %8, off offset:160 sc0 sc1\n\t" \
    "global_load_dwordx4 %6, %8, off offset:192 sc0 sc1\n\t" \
    "global_load_dwordx4 %7, %8, off offset:224 sc0 sc1" \
    : "=&v"(abuf[BUF][0]), "=&v"(abuf[BUF][1]), "=&v"(abuf[BUF][2]), "=&v"(abuf[BUF][3]), \
      "=&v"(abuf[BUF][4]), "=&v"(abuf[BUF][5]), "=&v"(abuf[BUF][6]), "=&v"(abuf[BUF][7]) \
    : "v"(P) : "memory")

#define ISSUE_STG8(P0,P1,P2,P3,P4,P5,P6,P7) asm volatile( \
    "global_load_dwordx4 %0, %8, off sc0 sc1\n\t" \
    "global_load_dwordx4 %1, %9, off sc0 sc1\n\t" \
    "global_load_dwordx4 %2, %10, off sc0 sc1\n\t" \
    "global_load_dwordx4 %3, %11, off sc0 sc1\n\t" \
    "global_load_dwordx4 %4, %12, off sc0 sc1\n\t" \
    "global_load_dwordx4 %5, %13, off sc0 sc1\n\t" \
    "global_load_dwordx4 %6, %14, off sc0 sc1\n\t" \
    "global_load_dwordx4 %7, %15, off sc0 sc1" \
    : "=&v"(sreg[0]), "=&v"(sreg[1]), "=&v"(sreg[2]), "=&v"(sreg[3]), \
      "=&v"(sreg[4]), "=&v"(sreg[5]), "=&v"(sreg[6]), "=&v"(sreg[7]) \
    : "v"(P0), "v"(P1), "v"(P2), "v"(P3), "v"(P4), "v"(P5), "v"(P6), "v"(P7) \
    : "memory")

// prologue issue of chunk c0+J into buffer J (x-cached if c<2, else coherent state)
#define GM_PRO(J) do { \
    const int c_ = c0 + (J); \
    if (c_ < 2) { const char* p_ = xrow + c_ * 256;  ISSUE_AX(J, p_); } \
    else        { const char* p_ = sprow + c_ * 256; ISSUE_AS(J, p_); } \
} while (0)

// REC chunk iteration, 4 buffers: counted wait, compute, then reissue 4 ahead
#define GM_ITR(I, WN, DOISS) do { \
    WAITV(WN); \
    _Pragma("unroll") \
    for (int kb = 0; kb < 8; ++kb) { \
        f16x8 bf = *(const f16x8*)(smem + addrB[kb] + (I) * 256); \
        if (kb & 1) acc1 = __builtin_amdgcn_mfma_f32_32x32x16_f16(abuf[(I) & 3][kb], bf, acc1, 0, 0, 0); \
        else        acc0 = __builtin_amdgcn_mfma_f32_32x32x16_f16(abuf[(I) & 3][kb], bf, acc0, 0, 0, 0); \
    } \
    SCHEDB; \
    if (DOISS) { const char* p_ = sprow + (c0 + (I) + 4) * 256; ISSUE_AS(((I) & 3), p_); } \
} while (0)

// ACT chunk iteration, 3 buffers
#define GM_ITA(I, WN, DOISS) do { \
    WAITV(WN); \
    _Pragma("unroll") \
    for (int kb = 0; kb < 8; ++kb) { \
        f16x8 bf = *(const f16x8*)(smem + addrB[kb] + (I) * 256); \
        if (kb & 1) acc1 = __builtin_amdgcn_mfma_f32_32x32x16_f16(abuf[(I) % 3][kb], bf, acc1, 0, 0, 0); \
        else        acc0 = __builtin_amdgcn_mfma_f32_32x32x16_f16(abuf[(I) % 3][kb], bf, acc0, 0, 0, 0); \
    } \
    SCHEDB; \
    if (DOISS) { const char* p_ = sprow + (c0 + (I) + 3) * 256; ISSUE_AS(((I) % 3), p_); } \
} while (0)

__device__ __forceinline__ void st_coh_h(f16* p, float vf) {
    union { f16 h; short s; } u; u.h = (f16)vf;
    asm volatile("global_store_short %0, %1, off sc0 sc1" :: "v"(p), "v"((int)u.s) : "memory");
}

__device__ __forceinline__ float fast_tanh(float x) {
    float e = __expf(2.f * x);
    return 1.f - 2.f / (e + 1.f);
}

__device__ __forceinline__ unsigned ld_rlx(unsigned* p) {
    return __hip_atomic_load(p, __ATOMIC_RELAXED, __HIP_MEMORY_SCOPE_AGENT);
}

__device__ __forceinline__ void arriveA(unsigned* bar, int blk) {
    unsigned old = __hip_atomic_fetch_add(&bar[(blk & 7) * 16], 1u, __ATOMIC_RELAXED, __HIP_MEMORY_SCOPE_AGENT);
    if ((old & 7u) == 7u) {
        unsigned r = __hip_atomic_fetch_add(&bar[MIDA], 1u, __ATOMIC_RELAXED, __HIP_MEMORY_SCOPE_AGENT);
        if ((r & 7u) == 7u)
            __hip_atomic_fetch_add(&bar[FLAGA], 1u, __ATOMIC_RELAXED, __HIP_MEMORY_SCOPE_AGENT);
    }
}
__device__ __forceinline__ void arriveB(unsigned* bar, int a) {
    unsigned old = __hip_atomic_fetch_add(&bar[160 + (a & 7) * 16], 1u, __ATOMIC_RELAXED, __HIP_MEMORY_SCOPE_AGENT);
    if ((old & 3u) == 3u) {
        unsigned r = __hip_atomic_fetch_add(&bar[MIDB], 1u, __ATOMIC_RELAXED, __HIP_MEMORY_SCOPE_AGENT);
        if ((r & 7u) == 7u)
            __hip_atomic_fetch_add(&bar[FLAGB], 1u, __ATOMIC_RELAXED, __HIP_MEMORY_SCOPE_AGENT);
    }
}

// init: zero barriers+state, convert x [B,T,I] f32 -> x16 [T,B,I] f16
__global__ void init_kernel(const float* __restrict__ x, char* __restrict__ ws) {
    const int gid = blockIdx.x * THREADS + threadIdx.x;
    if (blockIdx.x == 0) {
        for (int i = threadIdx.x; i < 512; i += THREADS) ((unsigned*)ws)[i] = 0u;
    }
    f16* x16 = (f16*)(ws + OFF_X16);
    const int NQ = T_ * B_ * (I_ / 4);
    for (int q = gid; q < NQ; q += 256 * THREADS) {
        int t = q >> 12;
        int rem = q & 4095;
        int b = rem >> 6;
        int k4 = rem & 63;
        f32x4 v = *(const f32x4*)(x + ((size_t)b * T_ + t) * I_ + k4 * 4);
        f16x4 h;
        h[0] = (f16)v[0]; h[1] = (f16)v[1]; h[2] = (f16)v[2]; h[3] = (f16)v[3];
        *(f16x4*)(x16 + ((size_t)t * B_ + b) * I_ + k4 * 4) = h;
    }
    f16x8 z = {0, 0, 0, 0, 0, 0, 0, 0};
    f16* xp0 = (f16*)(ws + OFF_XP3);
    for (int e = gid * 8; e < B_ * IM_; e += 256 * THREADS * 8) *(f16x8*)(xp0 + e) = z;
    f16* h0 = (f16*)(ws + OFF_H2);
    for (int e = gid * 8; e < B_ * O_; e += 256 * THREADS * 8) *(f16x8*)(h0 + e) = z;
}

__global__ __launch_bounds__(THREADS, 1) void cwrnn_kernel(
    const float* __restrict__ x, const float* __restrict__ W_in, const float* __restrict__ b_in,
    const float* __restrict__ W_h, const float* __restrict__ W_ir, const float* __restrict__ b_ir,
    const float* __restrict__ W_hr, const float* __restrict__ periods, const float* __restrict__ shifts,
    float* __restrict__ out, char* __restrict__ ws)
{
    __shared__ __align__(16) char smem[157696];
    // REC: W[32][2304] swz @0 (147456) | accx @147456 (10240)
    // ACT: W[32][1280] swz @0 (81920) | xp_raw @81920 (32768) | accx @114688 (10240)
    //      lse @124928 | part @125952 | gate @126976

    unsigned* bar = (unsigned*)ws;
    const int blk = blockIdx.x, tid = threadIdx.x;
    const int lane = tid & 63, w = tid >> 6;
    const int col = lane & 31, g = lane >> 5;
    const int pair = w >> 1;
    const int arow = ((w & 1) << 5) + col;

    float* ys = out;
    float* hfin = out + (size_t)B_ * T_ * O_;
    float* ps = hfin + (size_t)B_ * O_;

    if (blk < NREC) {
        // ================= x_pred recurrence blocks: cols j0..j0+31 of acts_rec =================
        const int j0 = blk * 32;
        {   // stage W2 = [W_ir | W_hr] rows j0..j0+31 into swizzled LDS (once)
            const int j = tid >> 3;
            const float* ra = W_ir + (size_t)(j0 + j) * I_;
            const float* rb = W_hr + (size_t)(j0 + j) * IM_ - 256;
            for (int u = (tid & 7); u < 288; u += 8) {
                int k0 = u * 8;
                const float* s = (k0 < 256) ? (ra + k0) : (rb + k0);
                f32x4 lo = *(const f32x4*)s;
                f32x4 hi = *(const f32x4*)(s + 4);
                f16x8 v;
                #pragma unroll
                for (int e = 0; e < 4; ++e) { v[e] = (f16)lo[e]; v[e + 4] = (f16)hi[e]; }
                *(f16x8*)(smem + j * 4608 + ((u ^ (j & 15)) << 4)) = v;
            }
        }
        const float bir = b_ir[j0 + col];
        LGKM0; BARRIER;

        int addrB[8];
        const int c0 = pair * 9;
        #pragma unroll
        for (int kb = 0; kb < 8; ++kb)
            addrB[kb] = col * 4608 + ((((kb << 1) + g) ^ (col & 15)) << 4) + c0 * 256;

        const char* xrow0 = (const char*)(ws + OFF_X16) + (size_t)arow * 512 + g * 16;
        f16* const xpB = (f16*)(ws + OFF_XP3);

        for (int t = 0; t < T_ - 1; ++t) {
            if (tid == 0) {
                while (1) {
                    int fa = (int)ld_rlx(&bar[FLAGA]);
                    int fb = (int)ld_rlx(&bar[FLAGB]);
                    if (fa >= t && fb >= t - 1) break;
                    __builtin_amdgcn_s_sleep(1);
                }
            }
            BARRIER;
            const int bi = t % 3;
            int bn = bi + 1; if (bn == 3) bn = 0;
            const f16* xpcur = xpB + (size_t)bi * B_ * IM_;
            f16* xpnxt = xpB + (size_t)bn * B_ * IM_;
            const char* sprow = (const char*)xpcur + (size_t)arow * 4096 + g * 16 - 512;
            const char* xrow = xrow0 + (size_t)t * 32768;

            f16x8 abuf[4][8];
            f32x16 acc0, acc1;
            #pragma unroll
            for (int r = 0; r < 16; ++r) { acc0[r] = 0.f; acc1[r] = 0.f; }

            GM_PRO(0); GM_PRO(1); GM_PRO(2); GM_PRO(3);
            GM_ITR(0, 24, 1); GM_ITR(1, 24, 1); GM_ITR(2, 24, 1); GM_ITR(3, 24, 1);
            GM_ITR(4, 24, 1); GM_ITR(5, 24, 0); GM_ITR(6, 16, 0); GM_ITR(7, 8, 0); GM_ITR(8, 0, 0);

            f32x16 accS;
            #pragma unroll
            for (int r = 0; r < 16; ++r) accS[r] = acc0[r] + acc1[r];
            if (w >= 2) {
                char* axp = smem + 147456 + (w - 2) * 5120 + lane * 80;
                #pragma unroll
                for (int q = 0; q < 4; ++q) {
                    f32x4 v = { accS[q * 4 + 0], accS[q * 4 + 1], accS[q * 4 + 2], accS[q * 4 + 3] };
                    *(f32x4*)(axp + q * 16) = v;
                }
            }
            LGKM0; BARRIER;
            if (w < 2) {
                const char* axp = smem + 147456 + w * 5120 + lane * 80;
                #pragma unroll
                for (int q = 0; q < 4; ++q) {
                    f32x4 v = *(const f32x4*)(axp + q * 16);
                    accS[q * 4 + 0] += v[0]; accS[q * 4 + 1] += v[1];
                    accS[q * 4 + 2] += v[2]; accS[q * 4 + 3] += v[3];
                }
                #pragma unroll
                for (int r = 0; r < 16; ++r) {
                    int row = (r & 3) + ((r >> 2) << 3) + (g << 2) + (w << 5);
                    st_coh_h(xpnxt + (size_t)row * IM_ + j0 + col, fast_tanh(accS[r] + bir));
                }
            }
            WAITV(0);
            BARRIER;
            if (tid == 0) arriveA(bar, blk);
        }
    } else {
        // ================= acts/gate/output blocks: cols o0..o0+31 =================
        const int a = blk - NREC;
        const int m = a >> 2;
        const int o0 = a * 32;
        {   // stage W1 = [W_in | W_h] rows o0..o0+31
            const int j = tid >> 3;
            const float* ra = W_in + (size_t)(o0 + j) * I_;
            const float* rb = W_h + (size_t)(o0 + j) * O_ - 256;
            for (int u = (tid & 7); u < 160; u += 8) {
                int k0 = u * 8;
                const float* s = (k0 < 256) ? (ra + k0) : (rb + k0);
                f32x4 lo = *(const f32x4*)s;
                f32x4 hi = *(const f32x4*)(s + 4);
                f16x8 v;
                #pragma unroll
                for (int e = 0; e < 4; ++e) { v[e] = (f16)lo[e]; v[e + 4] = (f16)hi[e]; }
                *(f16x8*)(smem + j * 2560 + ((u ^ (j & 15)) << 4)) = v;
            }
        }
        const float bin = b_in[o0 + col];
        const float per = periods[m], shf = shifts[m];
        LGKM0; BARRIER;

        int addrB[8];
        const int c0 = pair * 5;
        #pragma unroll
        for (int kb = 0; kb < 8; ++kb)
            addrB[kb] = col * 2560 + ((((kb << 1) + g) ^ (col & 15)) << 4) + c0 * 256;

        char* xp_raw = smem + 81920;
        float* lse_lds = (float*)(smem + 124928);
        float* part_lds = (float*)(smem + 125952);
        float* gate_lds = (float*)(smem + 126976);

        const char* xrow0 = (const char*)(ws + OFF_X16) + (size_t)arow * 512 + g * 16;
        const f16* xpB = (const f16*)(ws + OFF_XP3);
        f16* h2 = (f16*)(ws + OFF_H2);
        const int t5 = tid >> 5, cg = tid & 31;
        float hreg[16];
        #pragma unroll
        for (int r = 0; r < 16; ++r) hreg[r] = 0.f;

        for (int t = 0; t < T_; ++t) {
            if (tid == 0) {
                while (1) {
                    int fa = (int)ld_rlx(&bar[FLAGA]);
                    int fb = (int)ld_rlx(&bar[FLAGB]);
                    if (fa >= t && fb >= t) break;
                    __builtin_amdgcn_s_sleep(1);
                }
            }
            BARRIER;
            const int bi = t % 3;
            const f16* xpcur = xpB + (size_t)bi * B_ * IM_;
            const f16* hcur = h2 + (size_t)(t & 1) * B_ * O_;
            f16* hnxt = h2 + (size_t)((t + 1) & 1) * B_ * O_;

            // issue softmax-slice staging loads first (latency hidden under GEMM)
            f16x8 sreg[8];
            {
                const char* sb = (const char*)xpcur + (size_t)m * 512 + (size_t)cg * 16 + (size_t)t5 * 4096;
                ISSUE_STG8(sb, sb + 32768, sb + 2 * 32768, sb + 3 * 32768,
                           sb + 4 * 32768, sb + 5 * 32768, sb + 6 * 32768, sb + 7 * 32768);
            }

            const char* sprow = (const char*)hcur + (size_t)arow * 2048 + g * 16 - 512;
            const char* xrow = xrow0 + (size_t)t * 32768;
            f16x8 abuf[3][8];
            f32x16 acc0, acc1;
            #pragma unroll
            for (int r = 0; r < 16; ++r) { acc0[r] = 0.f; acc1[r] = 0.f; }

            GM_PRO(0); GM_PRO(1); GM_PRO(2);
            // it0: wait sreg + c0; park sreg; compute c0; issue c3
            WAITV(16);
            {
                const int gsw = (cg ^ t5) << 4;
                #pragma unroll
                for (int k = 0; k < 8; ++k)
                    *(f16x8*)(xp_raw + (size_t)(t5 + (k << 3)) * 512 + gsw) = sreg[k];
            }
            #pragma unroll
            for (int kb = 0; kb < 8; ++kb) {
                f16x8 bf = *(const f16x8*)(smem + addrB[kb]);
                if (kb & 1) acc1 = __builtin_amdgcn_mfma_f32_32x32x16_f16(abuf[0][kb], bf, acc1, 0, 0, 0);
                else        acc0 = __builtin_amdgcn_mfma_f32_32x32x16_f16(abuf[0][kb], bf, acc0, 0, 0, 0);
            }
            SCHEDB;
            { const char* p_ = sprow + (c0 + 3) * 256; ISSUE_AS(0, p_); }
            GM_ITA(1, 16, 1); GM_ITA(2, 16, 0); GM_ITA(3, 8, 0); GM_ITA(4, 0, 0);

            f32x16 accS;
            #pragma unroll
            for (int r = 0; r < 16; ++r) accS[r] = acc0[r] + acc1[r];
            if (w >= 2) {
                char* axp = smem + 114688 + (w - 2) * 5120 + lane * 80;
                #pragma unroll
                for (int q = 0; q < 4; ++q) {
                    f32x4 v = { accS[q * 4 + 0], accS[q * 4 + 1], accS[q * 4 + 2], accS[q * 4 + 3] };
                    *(f32x4*)(axp + q * 16) = v;
                }
            }
            LGKM0; BARRIER;
            {   // lse over batch axis, feature i = tid
                int i = tid;
                int gq = i >> 3, r2 = (i & 7) * 2;
                float mx = -1e30f;
                #pragma unroll 8
                for (int b = 0; b < B_; ++b)
                    mx = fmaxf(mx, (float)*(const f16*)(xp_raw + b * 512 + ((gq ^ (b & 7)) << 4) + r2));
                float s = 0.f;
                #pragma unroll 8
                for (int b = 0; b < B_; ++b)
                    s += __expf((float)*(const f16*)(xp_raw + b * 512 + ((gq ^ (b & 7)) << 4) + r2) - mx);
                lse_lds[i] = mx + __logf(s);
            }
            LGKM0; BARRIER;
            {   // mean surprisal partial dots: thread = (b, quarter)
                int b = tid >> 2, q = tid & 3;
                const float* xr = x + ((size_t)b * T_ + t) * I_ + q * 64;
                float s = 0.f;
                #pragma unroll
                for (int k = 0; k < 8; ++k) {
                    f16x8 xp8 = *(const f16x8*)(xp_raw + (size_t)b * 512 + ((((q << 3) + k) ^ (b & 7)) << 4));
                    f32x4 xa = *(const f32x4*)(xr + k * 8);
                    f32x4 xb2 = *(const f32x4*)(xr + k * 8 + 4);
                    #pragma unroll
                    for (int jj = 0; jj < 4; ++jj)
                        s += ((float)xp8[jj] - lse_lds[(q << 6) + (k << 3) + jj]) * xa[jj];
                    #pragma unroll
                    for (int jj = 0; jj < 4; ++jj)
                        s += ((float)xp8[jj + 4] - lse_lds[(q << 6) + (k << 3) + 4 + jj]) * xb2[jj];
                }
                part_lds[tid] = s;
            }
            LGKM0; BARRIER;
            if (tid < B_) {
                float s = part_lds[tid * 4] + part_lds[tid * 4 + 1] + part_lds[tid * 4 + 2] + part_lds[tid * 4 + 3];
                float mp = (s * (1.f / 256.f)) * per;
                gate_lds[tid] = 0.5f * (sinf((float)t * mp + shf) + 1.f);
                if ((a & 3) == 0) ps[((size_t)tid * T_ + t) * M_ + m] = mp;
            }
            LGKM0; BARRIER;
            if (w < 2) {
                const char* axp = smem + 114688 + w * 5120 + lane * 80;
                #pragma unroll
                for (int q = 0; q < 4; ++q) {
                    f32x4 v = *(const f32x4*)(axp + q * 16);
                    accS[q * 4 + 0] += v[0]; accS[q * 4 + 1] += v[1];
                    accS[q * 4 + 2] += v[2]; accS[q * 4 + 3] += v[3];
                }
                #pragma unroll
                for (int r = 0; r < 16; ++r) {
                    int row = (r & 3) + ((r >> 2) << 3) + (g << 2) + (w << 5);
                    float gt = gate_lds[row];
                    float av = fast_tanh(accS[r] + bin);
                    float y = (1.f - gt) * av + gt * hreg[r];
                    hreg[r] = y;
                    ys[((size_t)row * T_ + t) * O_ + o0 + col] = y;
                    st_coh_h(hnxt + (size_t)row * O_ + o0 + col, y);
                    if (t == T_ - 1) hfin[(size_t)row * O_ + o0 + col] = y;
                }
            }
            WAITV(0);
            BARRIER;
            if (tid == 0) arriveB(bar, a);
        }
    }
}

extern "C" void kernel_launch(void* const* d_in, const int* in_sizes, int n_in,
                              void* d_out, int out_size, void* d_ws, size_t ws_size,
                              hipStream_t stream) {
    const float* x    = (const float*)d_in[0];
    const float* W_in = (const float*)d_in[1];
    const float* b_in = (const float*)d_in[2];
    const float* W_h  = (const float*)d_in[3];
    const float* W_ir = (const float*)d_in[4];
    const float* b_ir = (const float*)d_in[5];
    const float* W_hr = (const float*)d_in[6];
    const float* per  = (const float*)d_in[7];
    const float* shf  = (const float*)d_in[8];

    hipLaunchKernelGGL(init_kernel, dim3(256), dim3(THREADS), 0, stream,
                       x, (char*)d_ws);
    hipLaunchKernelGGL(cwrnn_kernel, dim3(NB), dim3(THREADS), 0, stream,
                       x, W_in, b_in, W_h, W_ir, b_ir, W_hr, per, shf,
                       (float*)d_out, (char*)d_ws);
}